// Round 10
// baseline (515.540 us; speedup 1.0000x reference)
//
#include <hip/hip_runtime.h>

#define BN 8192
#define GIN 768
#define SL 1344   // per-entry LDS slice (floats)

// ---- ws layout (bytes), total ~18.5 MB ----
#define O_ROUTE_I 0UL                                   // int[BN][2]
#define O_ROUTE_W (O_ROUTE_I + (size_t)BN*2*4)          // float[BN][2]
#define O_COUNTS  (O_ROUTE_W + (size_t)BN*2*4)          // int[8] (padded to 256B)
#define O_LISTS   (O_COUNTS + 256)                      // int[8][BN]
#define O_PW2T    (O_LISTS + (size_t)8*BN*4)            // float[8][64][128]
#define O_PW3T    (O_PW2T + (size_t)8*64*128*4)         // float[8][128][256]
#define O_SLOT    (O_PW3T + (size_t)8*128*256*4)        // float[2*BN][256]

// ---------------- K0: weight transpose + zero counters ----------------
__global__ __launch_bounds__(256) void k0_prep(const float* __restrict__ pw2w,
                                               const float* __restrict__ pw3w,
                                               float* __restrict__ pw2t,
                                               float* __restrict__ pw3t,
                                               int* __restrict__ counts)
{
    int tid = blockIdx.x * 256 + threadIdx.x;
    if (tid < 8) counts[tid] = 0;
    for (int idx = tid; idx < 8 * 128 * 64; idx += 256 * 256) {
        int e = idx >> 13; int r = idx & 8191; int oc = r >> 6; int c = r & 63;
        pw2t[(size_t)e * 8192 + c * 128 + oc] = pw2w[idx];
    }
    for (int idx = tid; idx < 8 * 256 * 128; idx += 256 * 256) {
        int e = idx >> 15; int r = idx & 32767; int oc = r >> 7; int c = r & 127;
        pw3t[(size_t)e * 32768 + c * 256 + oc] = pw3w[idx];
    }
}

// ---------------- K1: gate GEMM + top2 + list build ----------------
// grid 1024 blocks (4/CU); tile = 8 patches x 128 hidden, Kc=32.
// Per-output k-summation order identical to previous rounds (bit-exact logits).
__global__ __launch_bounds__(256) void k1_gate(
    const float* __restrict__ x, const float* __restrict__ w1,
    const float* __restrict__ b1, const float* __restrict__ w2,
    const float* __restrict__ b2,
    int* __restrict__ route_i, float* __restrict__ route_w,
    int* __restrict__ counts, int* __restrict__ lists)
{
    __shared__ __align__(16) float A[32][12];    // [k][p], p<8, rows 48B
    __shared__ __align__(16) float Wl[32][132];  // [k][h]
    __shared__ float hl[8][132];
    __shared__ float ll[8][8];

    int tid = threadIdx.x;
    int pblk = blockIdx.x * 8;

    int pgrp = tid & 3;        // p0 = pgrp*2
    int hgrp = tid >> 2;       // h0 = hgrp*2 (0..126)
    float acc[2][2] = {};

    int sp  = tid >> 4;        // patch-local 0..7 (A staging, tid<128)
    int sk2 = (tid & 15) * 2;  // k offset 0..30
    int swh = tid >> 1;        // h 0..127 (W staging)
    int swk = (tid & 1) * 16;  // k offset 0 / 16

    int patchA = pblk + sp;
    int bA = patchA >> 8; int nA = patchA & 255; int hpA = nA >> 4; int wpA = nA & 15;

    for (int kc = 0; kc < GIN; kc += 32) {
        if (tid < 128) {   // stage A (8p x 32k) transposed to [k][p]
            int k = kc + sk2;
            int c = k >> 8; int rem = k & 255; int ri = rem >> 4; int j = rem & 15;
            const float* src = x + (((size_t)(bA * 3 + c) * 256 + hpA * 16 + ri) * 256 + wpA * 16 + j);
            float2 a2 = *reinterpret_cast<const float2*>(src);
            A[sk2][sp] = a2.x; A[sk2 + 1][sp] = a2.y;
        }
        {   // stage W (128h x 32k) transposed to [k][h]
            const float* wsrc = w1 + (size_t)swh * GIN + kc + swk;
            #pragma unroll
            for (int qq = 0; qq < 4; qq++) {
                float4 w4 = *reinterpret_cast<const float4*>(wsrc + qq * 4);
                Wl[swk + qq * 4 + 0][swh] = w4.x; Wl[swk + qq * 4 + 1][swh] = w4.y;
                Wl[swk + qq * 4 + 2][swh] = w4.z; Wl[swk + qq * 4 + 3][swh] = w4.w;
            }
        }
        __syncthreads();
        float cacc[2][2] = {};
        #pragma unroll
        for (int k2 = 0; k2 < 32; k2++) {
            float2 av = *reinterpret_cast<const float2*>(&A[k2][pgrp * 2]);
            float2 wv = *reinterpret_cast<const float2*>(&Wl[k2][hgrp * 2]);
            cacc[0][0] += av.x * wv.x; cacc[0][1] += av.x * wv.y;
            cacc[1][0] += av.y * wv.x; cacc[1][1] += av.y * wv.y;
        }
        #pragma unroll
        for (int i = 0; i < 2; i++) {
            #pragma unroll
            for (int jj = 0; jj < 2; jj++) acc[i][jj] += cacc[i][jj];
        }
        __syncthreads();
    }

    #pragma unroll
    for (int jj = 0; jj < 2; jj++) {
        float bb = b1[hgrp * 2 + jj];
        #pragma unroll
        for (int i = 0; i < 2; i++) {
            float v = acc[i][jj] + bb;
            hl[pgrp * 2 + i][hgrp * 2 + jj] = v > 0.f ? v : 0.f;
        }
    }
    __syncthreads();

    if (tid < 64) {
        int lp = tid >> 3; int le = tid & 7;
        float lacc = b2[le];
        const float* wrow = w2 + le * 128;
        for (int h = 0; h < 128; h++) lacc += hl[lp][h] * wrow[h];
        ll[lp][le] = lacc;
    }
    __syncthreads();

    if (tid < 8) {
        int patch = pblk + tid;
        float v[8];
        #pragma unroll
        for (int e = 0; e < 8; e++) v[e] = ll[tid][e];
        int e0 = 0; float m0 = v[0];
        #pragma unroll
        for (int e = 1; e < 8; e++) if (v[e] > m0) { m0 = v[e]; e0 = e; }
        int e1 = -1; float m1 = -3.0e38f;
        #pragma unroll
        for (int e = 0; e < 8; e++) if (e != e0 && v[e] > m1) { m1 = v[e]; e1 = e; }
        float t = expf(m1 - m0);
        float w0 = 1.f / (1.f + t);
        float w1v = t * w0;
        route_i[patch * 2] = e0; route_i[patch * 2 + 1] = e1;
        route_w[patch * 2] = w0; route_w[patch * 2 + 1] = w1v;
        int p0 = atomicAdd(&counts[e0], 1);
        lists[e0 * BN + p0] = patch * 2;
        int p1 = atomicAdd(&counts[e1], 1);
        lists[e1 * BN + p1] = patch * 2 + 1;
    }
}

// pw1 row helper: identical expression to prior rounds (bit-exact)
__device__ __forceinline__ void pw1_row(const float* __restrict__ d1, int row,
                                        float pb, float pw0, float pw1v, float pw2v,
                                        float* __restrict__ dst)
{
    const float* d1b = d1 + row * 8;
    float4 x0 = *reinterpret_cast<const float4*>(&d1b[0]);
    float4 x1 = *reinterpret_cast<const float4*>(&d1b[4]);
    float4 y0 = *reinterpret_cast<const float4*>(&d1b[64]);
    float4 y1 = *reinterpret_cast<const float4*>(&d1b[68]);
    float4 z0 = *reinterpret_cast<const float4*>(&d1b[128]);
    float4 z1 = *reinterpret_cast<const float4*>(&d1b[132]);
    float v;
    v = pb + x0.x * pw0 + y0.x * pw1v + z0.x * pw2v; dst[0] = v > 0.f ? v : 0.f;
    v = pb + x0.y * pw0 + y0.y * pw1v + z0.y * pw2v; dst[1] = v > 0.f ? v : 0.f;
    v = pb + x0.z * pw0 + y0.z * pw1v + z0.z * pw2v; dst[2] = v > 0.f ? v : 0.f;
    v = pb + x0.w * pw0 + y0.w * pw1v + z0.w * pw2v; dst[3] = v > 0.f ? v : 0.f;
    v = pb + x1.x * pw0 + y1.x * pw1v + z1.x * pw2v; dst[4] = v > 0.f ? v : 0.f;
    v = pb + x1.y * pw0 + y1.y * pw1v + z1.y * pw2v; dst[5] = v > 0.f ? v : 0.f;
    v = pb + x1.z * pw0 + y1.z * pw1v + z1.z * pw2v; dst[6] = v > 0.f ? v : 0.f;
    v = pb + x1.w * pw0 + y1.w * pw1v + z1.w * pw2v; dst[7] = v > 0.f ? v : 0.f;
}

// ---------------- K23: expert pipeline, 4 entries/block, 1 wave/entry ----------
// BARRIER-FREE wave-private structure + fused pw2+relu+dw3 (R9) + slice 1344:
//   d2t @0     [64][18] = 1152  (C write, D read)
//   d3  @0     [128][4] =  512  (D write, F read)  aliases d2t: ALL D reads
//                                precede the d3 writes in wave program order
//   d1  @1152  [3][64]  =  192  (B write, C read)
// Phase A (x->LDS staging) DELETED: dw1 reads its 27 taps straight from
// global x (3KB patch, L1/L2-resident). Block LDS = 4x1344x4 = 21504 B ->
// 6 blocks/CU under the ~128KiB occupancy pool hypothesis (R9: 26624B gave
// the SAME 18.3% occupancy as 40960B => pool ~128KiB, 4-block cap at 26.6KB).
// Accumulation order per output unchanged everywhere -> bit-identical result.
__global__ __launch_bounds__(256, 4) void k23_expert(
    const float* __restrict__ x, const int* __restrict__ counts,
    const int* __restrict__ lists,
    const float* __restrict__ dw1w, const float* __restrict__ dw1b,
    const float* __restrict__ pw1w, const float* __restrict__ pw1b,
    const float* __restrict__ dw2w, const float* __restrict__ dw2b,
    const float* __restrict__ pw2t, const float* __restrict__ pw2b,
    const float* __restrict__ dw3w, const float* __restrict__ dw3b,
    const float* __restrict__ pw3t, const float* __restrict__ pw3b,
    float* __restrict__ slot)
{
    __shared__ __align__(16) float buf[4][SL];

    int e = blockIdx.x & 7;
    int chunk = blockIdx.x >> 3;
    int cnt = counts[e];
    int base = chunk * 4;
    if (base >= cnt) return;
    int tid = threadIdx.x;
    int en = tid >> 6; int l = tid & 63;       // one wave per entry
    if (base + en >= cnt) return;              // wave-uniform exit (no barriers)
    int pslot = lists[e * BN + base + en];     // wave-uniform scalar load
    int patch = pslot >> 1;
    int b = patch >> 8, nn = patch & 255, hp = nn >> 4, wp = nn & 15;

    float* d2t = buf[en];
    float* d3  = buf[en];
    float* d1  = buf[en] + 1152;

    // ---- phase B: dw1 3ch x 8x8, taps direct from global x ----
    {
        int oh = l >> 3, ow = l & 7;
        #pragma unroll
        for (int c = 0; c < 3; c++) {
            const float* xc = x + ((size_t)(b * 3 + c) * 256 + hp * 16) * 256 + wp * 16;
            const float* w9 = dw1w + (e * 3 + c) * 9;
            float acc = dw1b[e * 3 + c];
            #pragma unroll
            for (int ki = 0; ki < 3; ki++) {
                int ih = oh * 2 - 1 + ki;
                if ((unsigned)ih < 16u) {
                    #pragma unroll
                    for (int kj = 0; kj < 3; kj++) {
                        int iw = ow * 2 - 1 + kj;
                        if ((unsigned)iw < 16u) acc += xc[ih * 256 + iw] * w9[ki * 3 + kj];
                    }
                }
            }
            d1[c * 64 + l] = acc > 0.f ? acc : 0.f;
        }
    }

    // ---- phase C: pw1 fused with dw2, streaming 3-row window (lane = ch l) ----
    {
        const float* w3 = pw1w + (e * 64 + l) * 3;
        float pw0 = w3[0], pw1v = w3[1], pw2v = w3[2];
        float pb = pw1b[e * 64 + l];
        const float* w9 = dw2w + (e * 64 + l) * 9;
        float wd[9];
        #pragma unroll
        for (int i = 0; i < 9; i++) wd[i] = w9[i];
        float bd = dw2b[e * 64 + l];

        float rc[8] = {};
        float re[8], ro[8];

        #pragma unroll
        for (int oh = 0; oh < 4; oh++) {
            pw1_row(d1, oh * 2 + 0, pb, pw0, pw1v, pw2v, re);
            pw1_row(d1, oh * 2 + 1, pb, pw0, pw1v, pw2v, ro);
            #pragma unroll
            for (int ow = 0; ow < 4; ow++) {
                float acc = bd;
                if (oh > 0) {
                    #pragma unroll
                    for (int kj = 0; kj < 3; kj++) {
                        int iw = ow * 2 - 1 + kj;
                        if ((unsigned)iw < 8u) acc += rc[iw] * wd[kj];
                    }
                }
                #pragma unroll
                for (int kj = 0; kj < 3; kj++) {
                    int iw = ow * 2 - 1 + kj;
                    if ((unsigned)iw < 8u) acc += re[iw] * wd[3 + kj];
                }
                #pragma unroll
                for (int kj = 0; kj < 3; kj++) {
                    int iw = ow * 2 - 1 + kj;
                    if ((unsigned)iw < 8u) acc += ro[iw] * wd[6 + kj];
                }
                d2t[l * 18 + oh * 4 + ow] = acc > 0.f ? acc : 0.f;   // [ch][pos]
            }
            #pragma unroll
            for (int i = 0; i < 8; i++) rc[i] = ro[i];
        }
    }

    // ---- phase D+E fused: pw2 (K=64) + relu + dw3, lane l -> channels 2l,2l+1 --
    {
        int ch0 = 2 * l;
        const float* wbase = pw2t + (size_t)e * 8192;   // [c][128]
        float a0[16] = {}, a1[16] = {};                 // acc for ch0, ch0+1
        #pragma unroll 4
        for (int c = 0; c < 64; c++) {
            float2 w = *reinterpret_cast<const float2*>(wbase + c * 128 + ch0);
            const float* dr = d2t + c * 18;
            #pragma unroll
            for (int j = 0; j < 8; j++) {
                float2 av = *reinterpret_cast<const float2*>(dr + 2 * j);  // broadcast
                a0[2 * j]     += w.x * av.x;
                a0[2 * j + 1] += w.x * av.y;
                a1[2 * j]     += w.y * av.x;
                a1[2 * j + 1] += w.y * av.y;
            }
        }
        {
            float b0 = pw2b[e * 128 + ch0];
            float b1v = pw2b[e * 128 + ch0 + 1];
            #pragma unroll
            for (int p = 0; p < 16; p++) {
                float v0 = a0[p] + b0;  a0[p] = v0 > 0.f ? v0 : 0.f;
                float v1 = a1[p] + b1v; a1[p] = v1 > 0.f ? v1 : 0.f;
            }
        }
        {
            const float* w90 = dw3w + (e * 128 + ch0) * 9;
            const float* w91 = w90 + 9;
            float bb0 = dw3b[e * 128 + ch0];
            float bb1 = dw3b[e * 128 + ch0 + 1];
            float o0[4], o1[4];
            #pragma unroll
            for (int pos = 0; pos < 4; pos++) {
                int oh = pos >> 1, ow = pos & 1;
                float s0 = bb0, s1 = bb1;
                #pragma unroll
                for (int ki = 0; ki < 3; ki++) {
                    int ih = oh * 2 - 1 + ki;
                    if ((unsigned)ih < 4u) {
                        #pragma unroll
                        for (int kj = 0; kj < 3; kj++) {
                            int iw = ow * 2 - 1 + kj;
                            if ((unsigned)iw < 4u) {
                                s0 += a0[ih * 4 + iw] * w90[ki * 3 + kj];
                                s1 += a1[ih * 4 + iw] * w91[ki * 3 + kj];
                            }
                        }
                    }
                }
                o0[pos] = s0 > 0.f ? s0 : 0.f;
                o1[pos] = s1 > 0.f ? s1 : 0.f;
            }
            // d3 aliases d2t@0: all d2t reads above precede these writes (wave
            // program order; may-alias keeps order). Wave-private, no races.
            *reinterpret_cast<float4*>(&d3[ch0 * 4])     = make_float4(o0[0], o0[1], o0[2], o0[3]);
            *reinterpret_cast<float4*>(&d3[ch0 * 4 + 4]) = make_float4(o1[0], o1[1], o1[2], o1[3]);
        }
    }

    // ---- phase F: pw3 + avgpool: lane l -> oc l*4..+3, K=128 ----
    {
        int oc0 = l * 4;
        const float* wbase = pw3t + (size_t)e * 32768;   // [c][256]
        float acc[4][4] = {};
        #pragma unroll 4
        for (int c = 0; c < 128; c++) {
            float4 a = *reinterpret_cast<const float4*>(&d3[c * 4]);   // broadcast
            float4 w = *reinterpret_cast<const float4*>(wbase + c * 256 + oc0);
            float av[4] = {a.x, a.y, a.z, a.w};
            float wv[4] = {w.x, w.y, w.z, w.w};
            #pragma unroll
            for (int j = 0; j < 4; j++) {
                #pragma unroll
                for (int i = 0; i < 4; i++) acc[j][i] += wv[j] * av[i];
            }
        }
        float o4[4];
        #pragma unroll
        for (int j = 0; j < 4; j++) {
            float bb = pw3b[e * 256 + oc0 + j];
            float s = 0.f;
            #pragma unroll
            for (int i = 0; i < 4; i++) {
                float v = acc[j][i] + bb;
                s += (v > 0.f ? v : 0.f);
            }
            o4[j] = 0.25f * s;
        }
        *reinterpret_cast<float4*>(slot + (size_t)pslot * 256 + oc0) =
            make_float4(o4[0], o4[1], o4[2], o4[3]);
    }
}

// ---------------- K4: weighted combine + transpose to [B,D,16,16] ----------------
__global__ __launch_bounds__(256) void k4_comb(
    const float* __restrict__ slot, const float* __restrict__ route_w,
    float* __restrict__ out)
{
    __shared__ float cl[16][257];
    int bx = blockIdx.x;              // 0..511
    int b = bx >> 4; int hp = bx & 15;
    int tid = threadIdx.x;
    int d = tid;
    for (int wp = 0; wp < 16; wp++) {
        int n = (b * 16 + hp) * 16 + wp;
        float w0 = route_w[n * 2], w1 = route_w[n * 2 + 1];
        float v = w0 * slot[(size_t)(n * 2) * 256 + d] + w1 * slot[(size_t)(n * 2 + 1) * 256 + d];
        cl[wp][d] = v;
    }
    __syncthreads();
    int wp = tid & 15; int dg = tid >> 4;
    for (int r = 0; r < 16; r++) {
        int dd = r * 16 + dg;
        out[(((size_t)b * 256 + dd) * 16 + hp) * 16 + wp] = cl[wp][dd];
    }
    if (bx == 0 && tid == 0) out[(size_t)BN * 256] = 0.0f;
}

extern "C" void kernel_launch(void* const* d_in, const int* in_sizes, int n_in,
                              void* d_out, int out_size, void* d_ws, size_t ws_size,
                              hipStream_t stream)
{
    const float* x    = (const float*)d_in[0];
    const float* gw1  = (const float*)d_in[1];
    const float* gb1  = (const float*)d_in[2];
    const float* gw2  = (const float*)d_in[3];
    const float* gb2  = (const float*)d_in[4];
    const float* dw1w = (const float*)d_in[5];
    const float* dw1b = (const float*)d_in[6];
    const float* pw1w = (const float*)d_in[7];
    const float* pw1b = (const float*)d_in[8];
    const float* dw2w = (const float*)d_in[9];
    const float* dw2b = (const float*)d_in[10];
    const float* pw2w = (const float*)d_in[11];
    const float* pw2b = (const float*)d_in[12];
    const float* dw3w = (const float*)d_in[13];
    const float* dw3b = (const float*)d_in[14];
    const float* pw3w = (const float*)d_in[15];
    const float* pw3b = (const float*)d_in[16];

    char* ws = (char*)d_ws;
    int*   route_i = (int*)(ws + O_ROUTE_I);
    float* route_w = (float*)(ws + O_ROUTE_W);
    int*   counts  = (int*)(ws + O_COUNTS);
    int*   lists   = (int*)(ws + O_LISTS);
    float* pw2t    = (float*)(ws + O_PW2T);
    float* pw3t    = (float*)(ws + O_PW3T);
    float* slot    = (float*)(ws + O_SLOT);
    float* out     = (float*)d_out;

    hipLaunchKernelGGL(k0_prep, dim3(256), dim3(256), 0, stream,
                       pw2w, pw3w, pw2t, pw3t, counts);
    hipLaunchKernelGGL(k1_gate, dim3(BN / 8), dim3(256), 0, stream,
                       x, gw1, gb1, gw2, gb2, route_i, route_w, counts, lists);
    hipLaunchKernelGGL(k23_expert, dim3(8 * 2048), dim3(256), 0, stream,
                       x, counts, lists, dw1w, dw1b, pw1w, pw1b, dw2w, dw2b,
                       pw2t, pw2b, dw3w, dw3b, pw3t, pw3b, slot);
    hipLaunchKernelGGL(k4_comb, dim3(512), dim3(256), 0, stream,
                       slot, route_w, out);
}

// Round 11
// 472.104 us; speedup vs baseline: 1.0920x; 1.0920x over previous
//
#include <hip/hip_runtime.h>

#define BN 8192
#define GIN 768
#define SL 1472   // per-entry LDS slice (floats)

// ---- ws layout (bytes), total ~18.5 MB ----
#define O_ROUTE_I 0UL                                   // int[BN][2]
#define O_ROUTE_W (O_ROUTE_I + (size_t)BN*2*4)          // float[BN][2]
#define O_COUNTS  (O_ROUTE_W + (size_t)BN*2*4)          // int[8] (padded to 256B)
#define O_LISTS   (O_COUNTS + 256)                      // int[8][BN]
#define O_PW2T    (O_LISTS + (size_t)8*BN*4)            // float[8][64][128]
#define O_PW3T    (O_PW2T + (size_t)8*64*128*4)         // float[8][128][256]
#define O_SLOT    (O_PW3T + (size_t)8*128*256*4)        // float[2*BN][256]

// ---------------- K0: weight transpose + zero counters ----------------
__global__ __launch_bounds__(256) void k0_prep(const float* __restrict__ pw2w,
                                               const float* __restrict__ pw3w,
                                               float* __restrict__ pw2t,
                                               float* __restrict__ pw3t,
                                               int* __restrict__ counts)
{
    int tid = blockIdx.x * 256 + threadIdx.x;
    if (tid < 8) counts[tid] = 0;
    for (int idx = tid; idx < 8 * 128 * 64; idx += 256 * 256) {
        int e = idx >> 13; int r = idx & 8191; int oc = r >> 6; int c = r & 63;
        pw2t[(size_t)e * 8192 + c * 128 + oc] = pw2w[idx];
    }
    for (int idx = tid; idx < 8 * 256 * 128; idx += 256 * 256) {
        int e = idx >> 15; int r = idx & 32767; int oc = r >> 7; int c = r & 127;
        pw3t[(size_t)e * 32768 + c * 256 + oc] = pw3w[idx];
    }
}

// ---------------- K1: gate GEMM + top2 + list build (R9-best version) ----------
// grid 512 blocks; tile = 16 patches x 128 hidden, Kc=32. Bit-exact logits.
__global__ __launch_bounds__(256) void k1_gate(
    const float* __restrict__ x, const float* __restrict__ w1,
    const float* __restrict__ b1, const float* __restrict__ w2,
    const float* __restrict__ b2,
    int* __restrict__ route_i, float* __restrict__ route_w,
    int* __restrict__ counts, int* __restrict__ lists)
{
    __shared__ __align__(16) float A[32][20];    // [k][p]
    __shared__ __align__(16) float Wl[32][132];  // [k][h]
    __shared__ float hl[16][132];
    __shared__ float ll[16][8];

    int tid = threadIdx.x;
    int pblk = blockIdx.x * 16;

    int pgrp = tid & 7;        // p0 = pgrp*2
    int hgrp = tid >> 3;       // h0 = hgrp*4
    float acc[2][4] = {};

    int sp  = tid >> 4;        // patch-local 0..15 (A staging)
    int sk2 = (tid & 15) * 2;  // k offset 0..30
    int swh = tid >> 1;        // h 0..127 (W staging)
    int swk = (tid & 1) * 16;  // k offset 0 / 16

    int patchA = pblk + sp;
    int bA = patchA >> 8; int nA = patchA & 255; int hpA = nA >> 4; int wpA = nA & 15;

    for (int kc = 0; kc < GIN; kc += 32) {
        {
            int k = kc + sk2;
            int c = k >> 8; int rem = k & 255; int ri = rem >> 4; int j = rem & 15;
            const float* src = x + (((size_t)(bA * 3 + c) * 256 + hpA * 16 + ri) * 256 + wpA * 16 + j);
            float2 a2 = *reinterpret_cast<const float2*>(src);
            A[sk2][sp] = a2.x; A[sk2 + 1][sp] = a2.y;
        }
        {
            const float* wsrc = w1 + (size_t)swh * GIN + kc + swk;
            #pragma unroll
            for (int qq = 0; qq < 4; qq++) {
                float4 w4 = *reinterpret_cast<const float4*>(wsrc + qq * 4);
                Wl[swk + qq * 4 + 0][swh] = w4.x; Wl[swk + qq * 4 + 1][swh] = w4.y;
                Wl[swk + qq * 4 + 2][swh] = w4.z; Wl[swk + qq * 4 + 3][swh] = w4.w;
            }
        }
        __syncthreads();
        float cacc[2][4] = {};
        #pragma unroll
        for (int k2 = 0; k2 < 32; k2++) {
            float2 av = *reinterpret_cast<const float2*>(&A[k2][pgrp * 2]);
            float4 wv = *reinterpret_cast<const float4*>(&Wl[k2][hgrp * 4]);
            float aa[2] = {av.x, av.y};
            float ww[4] = {wv.x, wv.y, wv.z, wv.w};
            #pragma unroll
            for (int i = 0; i < 2; i++) {
                #pragma unroll
                for (int jj = 0; jj < 4; jj++) cacc[i][jj] += aa[i] * ww[jj];
            }
        }
        #pragma unroll
        for (int i = 0; i < 2; i++) {
            #pragma unroll
            for (int jj = 0; jj < 4; jj++) acc[i][jj] += cacc[i][jj];
        }
        __syncthreads();
    }

    #pragma unroll
    for (int jj = 0; jj < 4; jj++) {
        float bb = b1[hgrp * 4 + jj];
        #pragma unroll
        for (int i = 0; i < 2; i++) {
            float v = acc[i][jj] + bb;
            hl[pgrp * 2 + i][hgrp * 4 + jj] = v > 0.f ? v : 0.f;
        }
    }
    __syncthreads();

    if (tid < 128) {
        int lp = tid >> 3; int le = tid & 7;
        float lacc = b2[le];
        const float* wrow = w2 + le * 128;
        for (int h = 0; h < 128; h++) lacc += hl[lp][h] * wrow[h];
        ll[lp][le] = lacc;
    }
    __syncthreads();

    if (tid < 16) {
        int patch = pblk + tid;
        float v[8];
        #pragma unroll
        for (int e = 0; e < 8; e++) v[e] = ll[tid][e];
        int e0 = 0; float m0 = v[0];
        #pragma unroll
        for (int e = 1; e < 8; e++) if (v[e] > m0) { m0 = v[e]; e0 = e; }
        int e1 = -1; float m1 = -3.0e38f;
        #pragma unroll
        for (int e = 0; e < 8; e++) if (e != e0 && v[e] > m1) { m1 = v[e]; e1 = e; }
        float t = expf(m1 - m0);
        float w0 = 1.f / (1.f + t);
        float w1v = t * w0;
        route_i[patch * 2] = e0; route_i[patch * 2 + 1] = e1;
        route_w[patch * 2] = w0; route_w[patch * 2 + 1] = w1v;
        int p0 = atomicAdd(&counts[e0], 1);
        lists[e0 * BN + p0] = patch * 2;
        int p1 = atomicAdd(&counts[e1], 1);
        lists[e1 * BN + p1] = patch * 2 + 1;
    }
}

// pw1 row helper: identical expression to prior rounds (bit-exact)
__device__ __forceinline__ void pw1_row(const float* __restrict__ d1, int row,
                                        float pb, float pw0, float pw1v, float pw2v,
                                        float* __restrict__ dst)
{
    const float* d1b = d1 + row * 8;
    float4 x0 = *reinterpret_cast<const float4*>(&d1b[0]);
    float4 x1 = *reinterpret_cast<const float4*>(&d1b[4]);
    float4 y0 = *reinterpret_cast<const float4*>(&d1b[64]);
    float4 y1 = *reinterpret_cast<const float4*>(&d1b[68]);
    float4 z0 = *reinterpret_cast<const float4*>(&d1b[128]);
    float4 z1 = *reinterpret_cast<const float4*>(&d1b[132]);
    float v;
    v = pb + x0.x * pw0 + y0.x * pw1v + z0.x * pw2v; dst[0] = v > 0.f ? v : 0.f;
    v = pb + x0.y * pw0 + y0.y * pw1v + z0.y * pw2v; dst[1] = v > 0.f ? v : 0.f;
    v = pb + x0.z * pw0 + y0.z * pw1v + z0.z * pw2v; dst[2] = v > 0.f ? v : 0.f;
    v = pb + x0.w * pw0 + y0.w * pw1v + z0.w * pw2v; dst[3] = v > 0.f ? v : 0.f;
    v = pb + x1.x * pw0 + y1.x * pw1v + z1.x * pw2v; dst[4] = v > 0.f ? v : 0.f;
    v = pb + x1.y * pw0 + y1.y * pw1v + z1.y * pw2v; dst[5] = v > 0.f ? v : 0.f;
    v = pb + x1.z * pw0 + y1.z * pw1v + z1.z * pw2v; dst[6] = v > 0.f ? v : 0.f;
    v = pb + x1.w * pw0 + y1.w * pw1v + z1.w * pw2v; dst[7] = v > 0.f ? v : 0.f;
}

// ---------------- K23: expert pipeline, 4 entries/block, 1 wave/entry ----------
// BARRIER-FREE wave-private + fused pw2+relu+dw3 (R9), slice shrunk to 1472:
//   pl  @0     [3][16][20] = 960   (A write, B read)
//   d2t @0     [64][20]    = 1280  (C write, D read)  aliases dead pl
//   d3  @0     [128][4]    = 512   (D write, F read)  aliases d2t (all D reads
//                                   precede d3 writes in wave program order)
//   d1  @1280  [3][64]     = 192   (B write, C read)
// Block LDS = 4 x 1472 x 4 = 23552 B -> 6 blocks/CU at the 160KiB pool
// (R9/R10 occupancy fit: pool=160K -> 26624B:6blk vs 21504B:7blk = 18.4:21.7).
// d2t stride 20 (80B, 16B-aligned rows): C writes 2-way-free; D reads the 16
// positions as 4x ds_read_b128 broadcast (half the LDS ops of R9's float2).
// Accumulation order per output unchanged everywhere -> bit-identical result.
__global__ __launch_bounds__(256, 4) void k23_expert(
    const float* __restrict__ x, const int* __restrict__ counts,
    const int* __restrict__ lists,
    const float* __restrict__ dw1w, const float* __restrict__ dw1b,
    const float* __restrict__ pw1w, const float* __restrict__ pw1b,
    const float* __restrict__ dw2w, const float* __restrict__ dw2b,
    const float* __restrict__ pw2t, const float* __restrict__ pw2b,
    const float* __restrict__ dw3w, const float* __restrict__ dw3b,
    const float* __restrict__ pw3t, const float* __restrict__ pw3b,
    float* __restrict__ slot)
{
    __shared__ __align__(16) float buf[4][SL];

    int e = blockIdx.x & 7;
    int chunk = blockIdx.x >> 3;
    int cnt = counts[e];
    int base = chunk * 4;
    if (base >= cnt) return;
    int tid = threadIdx.x;
    int en = tid >> 6; int l = tid & 63;       // one wave per entry
    if (base + en >= cnt) return;              // wave-uniform exit (no barriers)
    int pslot = lists[e * BN + base + en];     // wave-uniform scalar load
    int patch = pslot >> 1;
    int b = patch >> 8, nn = patch & 255, hp = nn >> 4, wp = nn & 15;

    float* pl  = buf[en];
    float* d2t = buf[en];
    float* d3  = buf[en];
    float* d1  = buf[en] + 1280;

    // ---- phase A: stage patch [3][16][20] ----
    {
        int r = l >> 2; int j4 = (l & 3) * 4;
        #pragma unroll
        for (int c = 0; c < 3; c++) {
            const float* src = x + (((size_t)(b * 3 + c) * 256 + hp * 16 + r) * 256 + wp * 16 + j4);
            float4 v = *reinterpret_cast<const float4*>(src);
            *reinterpret_cast<float4*>(&pl[c * 320 + r * 20 + j4]) = v;
        }
    }

    // ---- phase B: dw1 3ch x 8x8 (taps from staged pl) ----
    {
        int oh = l >> 3, ow = l & 7;
        #pragma unroll
        for (int c = 0; c < 3; c++) {
            const float* w9 = dw1w + (e * 3 + c) * 9;
            float acc = dw1b[e * 3 + c];
            #pragma unroll
            for (int ki = 0; ki < 3; ki++) {
                int ih = oh * 2 - 1 + ki;
                if ((unsigned)ih < 16u) {
                    #pragma unroll
                    for (int kj = 0; kj < 3; kj++) {
                        int iw = ow * 2 - 1 + kj;
                        if ((unsigned)iw < 16u) acc += pl[c * 320 + ih * 20 + iw] * w9[ki * 3 + kj];
                    }
                }
            }
            d1[c * 64 + l] = acc > 0.f ? acc : 0.f;
        }
    }

    // ---- phase C: pw1 fused with dw2, streaming 3-row window (lane = ch l) ----
    // d2t writes alias dead pl (B's pl reads precede them in program order).
    {
        const float* w3 = pw1w + (e * 64 + l) * 3;
        float pw0 = w3[0], pw1v = w3[1], pw2v = w3[2];
        float pb = pw1b[e * 64 + l];
        const float* w9 = dw2w + (e * 64 + l) * 9;
        float wd[9];
        #pragma unroll
        for (int i = 0; i < 9; i++) wd[i] = w9[i];
        float bd = dw2b[e * 64 + l];

        float rc[8] = {};
        float re[8], ro[8];

        #pragma unroll
        for (int oh = 0; oh < 4; oh++) {
            pw1_row(d1, oh * 2 + 0, pb, pw0, pw1v, pw2v, re);
            pw1_row(d1, oh * 2 + 1, pb, pw0, pw1v, pw2v, ro);
            #pragma unroll
            for (int ow = 0; ow < 4; ow++) {
                float acc = bd;
                if (oh > 0) {
                    #pragma unroll
                    for (int kj = 0; kj < 3; kj++) {
                        int iw = ow * 2 - 1 + kj;
                        if ((unsigned)iw < 8u) acc += rc[iw] * wd[kj];
                    }
                }
                #pragma unroll
                for (int kj = 0; kj < 3; kj++) {
                    int iw = ow * 2 - 1 + kj;
                    if ((unsigned)iw < 8u) acc += re[iw] * wd[3 + kj];
                }
                #pragma unroll
                for (int kj = 0; kj < 3; kj++) {
                    int iw = ow * 2 - 1 + kj;
                    if ((unsigned)iw < 8u) acc += ro[iw] * wd[6 + kj];
                }
                d2t[l * 20 + oh * 4 + ow] = acc > 0.f ? acc : 0.f;   // [ch][pos]
            }
            #pragma unroll
            for (int i = 0; i < 8; i++) rc[i] = ro[i];
        }
    }

    // ---- phase D+E fused: pw2 (K=64) + relu + dw3, lane l -> channels 2l,2l+1 --
    {
        int ch0 = 2 * l;
        const float* wbase = pw2t + (size_t)e * 8192;   // [c][128]
        float a0[16] = {}, a1[16] = {};                 // acc for ch0, ch0+1
        #pragma unroll 4
        for (int c = 0; c < 64; c++) {
            float2 w = *reinterpret_cast<const float2*>(wbase + c * 128 + ch0);
            const float* dr = d2t + c * 20;
            float4 p0 = *reinterpret_cast<const float4*>(dr);        // broadcast
            float4 p1 = *reinterpret_cast<const float4*>(dr + 4);
            float4 p2 = *reinterpret_cast<const float4*>(dr + 8);
            float4 p3 = *reinterpret_cast<const float4*>(dr + 12);
            float pv[16] = {p0.x, p0.y, p0.z, p0.w, p1.x, p1.y, p1.z, p1.w,
                            p2.x, p2.y, p2.z, p2.w, p3.x, p3.y, p3.z, p3.w};
            #pragma unroll
            for (int p = 0; p < 16; p++) {
                a0[p] += w.x * pv[p];
                a1[p] += w.y * pv[p];
            }
        }
        {
            float b0 = pw2b[e * 128 + ch0];
            float b1v = pw2b[e * 128 + ch0 + 1];
            #pragma unroll
            for (int p = 0; p < 16; p++) {
                float v0 = a0[p] + b0;  a0[p] = v0 > 0.f ? v0 : 0.f;
                float v1 = a1[p] + b1v; a1[p] = v1 > 0.f ? v1 : 0.f;
            }
        }
        {
            const float* w90 = dw3w + (e * 128 + ch0) * 9;
            const float* w91 = w90 + 9;
            float bb0 = dw3b[e * 128 + ch0];
            float bb1 = dw3b[e * 128 + ch0 + 1];
            float o0[4], o1[4];
            #pragma unroll
            for (int pos = 0; pos < 4; pos++) {
                int oh = pos >> 1, ow = pos & 1;
                float s0 = bb0, s1 = bb1;
                #pragma unroll
                for (int ki = 0; ki < 3; ki++) {
                    int ih = oh * 2 - 1 + ki;
                    if ((unsigned)ih < 4u) {
                        #pragma unroll
                        for (int kj = 0; kj < 3; kj++) {
                            int iw = ow * 2 - 1 + kj;
                            if ((unsigned)iw < 4u) {
                                s0 += a0[ih * 4 + iw] * w90[ki * 3 + kj];
                                s1 += a1[ih * 4 + iw] * w91[ki * 3 + kj];
                            }
                        }
                    }
                }
                o0[pos] = s0 > 0.f ? s0 : 0.f;
                o1[pos] = s1 > 0.f ? s1 : 0.f;
            }
            // d3 aliases d2t@0: all d2t reads above precede these writes (wave
            // program order; may-alias keeps order). Wave-private, no races.
            *reinterpret_cast<float4*>(&d3[ch0 * 4])     = make_float4(o0[0], o0[1], o0[2], o0[3]);
            *reinterpret_cast<float4*>(&d3[ch0 * 4 + 4]) = make_float4(o1[0], o1[1], o1[2], o1[3]);
        }
    }

    // ---- phase F: pw3 + avgpool: lane l -> oc l*4..+3, K=128 ----
    {
        int oc0 = l * 4;
        const float* wbase = pw3t + (size_t)e * 32768;   // [c][256]
        float acc[4][4] = {};
        #pragma unroll 4
        for (int c = 0; c < 128; c++) {
            float4 a = *reinterpret_cast<const float4*>(&d3[c * 4]);   // broadcast
            float4 w = *reinterpret_cast<const float4*>(wbase + c * 256 + oc0);
            float av[4] = {a.x, a.y, a.z, a.w};
            float wv[4] = {w.x, w.y, w.z, w.w};
            #pragma unroll
            for (int j = 0; j < 4; j++) {
                #pragma unroll
                for (int i = 0; i < 4; i++) acc[j][i] += wv[j] * av[i];
            }
        }
        float o4[4];
        #pragma unroll
        for (int j = 0; j < 4; j++) {
            float bb = pw3b[e * 256 + oc0 + j];
            float s = 0.f;
            #pragma unroll
            for (int i = 0; i < 4; i++) {
                float v = acc[j][i] + bb;
                s += (v > 0.f ? v : 0.f);
            }
            o4[j] = 0.25f * s;
        }
        *reinterpret_cast<float4*>(slot + (size_t)pslot * 256 + oc0) =
            make_float4(o4[0], o4[1], o4[2], o4[3]);
    }
}

// ---------------- K4: weighted combine + transpose to [B,D,16,16] ----------------
__global__ __launch_bounds__(256) void k4_comb(
    const float* __restrict__ slot, const float* __restrict__ route_w,
    float* __restrict__ out)
{
    __shared__ float cl[16][257];
    int bx = blockIdx.x;              // 0..511
    int b = bx >> 4; int hp = bx & 15;
    int tid = threadIdx.x;
    int d = tid;
    for (int wp = 0; wp < 16; wp++) {
        int n = (b * 16 + hp) * 16 + wp;
        float w0 = route_w[n * 2], w1 = route_w[n * 2 + 1];
        float v = w0 * slot[(size_t)(n * 2) * 256 + d] + w1 * slot[(size_t)(n * 2 + 1) * 256 + d];
        cl[wp][d] = v;
    }
    __syncthreads();
    int wp = tid & 15; int dg = tid >> 4;
    for (int r = 0; r < 16; r++) {
        int dd = r * 16 + dg;
        out[(((size_t)b * 256 + dd) * 16 + hp) * 16 + wp] = cl[wp][dd];
    }
    if (bx == 0 && tid == 0) out[(size_t)BN * 256] = 0.0f;
}

extern "C" void kernel_launch(void* const* d_in, const int* in_sizes, int n_in,
                              void* d_out, int out_size, void* d_ws, size_t ws_size,
                              hipStream_t stream)
{
    const float* x    = (const float*)d_in[0];
    const float* gw1  = (const float*)d_in[1];
    const float* gb1  = (const float*)d_in[2];
    const float* gw2  = (const float*)d_in[3];
    const float* gb2  = (const float*)d_in[4];
    const float* dw1w = (const float*)d_in[5];
    const float* dw1b = (const float*)d_in[6];
    const float* pw1w = (const float*)d_in[7];
    const float* pw1b = (const float*)d_in[8];
    const float* dw2w = (const float*)d_in[9];
    const float* dw2b = (const float*)d_in[10];
    const float* pw2w = (const float*)d_in[11];
    const float* pw2b = (const float*)d_in[12];
    const float* dw3w = (const float*)d_in[13];
    const float* dw3b = (const float*)d_in[14];
    const float* pw3w = (const float*)d_in[15];
    const float* pw3b = (const float*)d_in[16];

    char* ws = (char*)d_ws;
    int*   route_i = (int*)(ws + O_ROUTE_I);
    float* route_w = (float*)(ws + O_ROUTE_W);
    int*   counts  = (int*)(ws + O_COUNTS);
    int*   lists   = (int*)(ws + O_LISTS);
    float* pw2t    = (float*)(ws + O_PW2T);
    float* pw3t    = (float*)(ws + O_PW3T);
    float* slot    = (float*)(ws + O_SLOT);
    float* out     = (float*)d_out;

    hipLaunchKernelGGL(k0_prep, dim3(256), dim3(256), 0, stream,
                       pw2w, pw3w, pw2t, pw3t, counts);
    hipLaunchKernelGGL(k1_gate, dim3(BN / 16), dim3(256), 0, stream,
                       x, gw1, gb1, gw2, gb2, route_i, route_w, counts, lists);
    hipLaunchKernelGGL(k23_expert, dim3(8 * 2048), dim3(256), 0, stream,
                       x, counts, lists, dw1w, dw1b, pw1w, pw1b, dw2w, dw2b,
                       pw2t, pw2b, dw3w, dw3b, pw3t, pw3b, slot);
    hipLaunchKernelGGL(k4_comb, dim3(512), dim3(256), 0, stream,
                       slot, route_w, out);
}